// Round 10
// baseline (407.006 us; speedup 1.0000x reference)
//
#include <hip/hip_runtime.h>

#define D 64

static __host__ __device__ inline int alignup(int x) { return (x + 63) & ~63; }

__device__ inline float blo(unsigned int u) { return __uint_as_float(u << 16); }
__device__ inline float bhi(unsigned int u) { return __uint_as_float(u & 0xffff0000u); }
__device__ inline unsigned short f2b(float f) {
    unsigned int u = __float_as_uint(f);
    return (unsigned short)((u + 0x7FFFu + ((u >> 16) & 1u)) >> 16);
}
__device__ inline unsigned int packb(float lo, float hi) {
    return (unsigned int)f2b(lo) | ((unsigned int)f2b(hi) << 16);
}

__global__ void init_cnt(int* __restrict__ cnt, int n) {
    int i = blockIdx.x * blockDim.x + threadIdx.x;
    if (i < n) cnt[i] = 0;
}

// ONE atomic per edge: slot position within row + final counts.
__global__ void histo_pos(const int* __restrict__ row, int* __restrict__ cnt,
                          int* __restrict__ aux, int E) {
    int e = blockIdx.x * blockDim.x + threadIdx.x;
    if (e < E) aux[e] = atomicAdd(&cnt[row[e]], 1);
}

__global__ void convert_bf16(const float* __restrict__ x, unsigned short* __restrict__ xb, long nElem) {
    long t = (long)blockIdx.x * blockDim.x + threadIdx.x;
    long i = t * 4;
    if (i + 3 < nElem) {
        float4 v = *(const float4*)(x + i);
        ushort4 o;
        o.x = f2b(v.x); o.y = f2b(v.y); o.z = f2b(v.z); o.w = f2b(v.w);
        *(ushort4*)(xb + i) = o;
    } else {
        for (long k = i; k < nElem; ++k) xb[k] = f2b(x[k]);
    }
}

__global__ void scan_block_sums(const int* __restrict__ cnt, int* __restrict__ bsums, int n) {
    __shared__ int s[256];
    int t = threadIdx.x;
    int i = blockIdx.x * 256 + t;
    s[t] = (i < n) ? cnt[i] : 0;
    __syncthreads();
    for (int st = 128; st > 0; st >>= 1) {
        if (t < st) s[t] += s[t + st];
        __syncthreads();
    }
    if (t == 0) bsums[blockIdx.x] = s[0];
}

__global__ void scan_bsums(int* __restrict__ bsums, int nb) {
    __shared__ int s[1024];
    int t = threadIdx.x;
    s[t] = (t < nb) ? bsums[t] : 0;
    __syncthreads();
    for (int off = 1; off < 1024; off <<= 1) {
        int v = 0;
        if (t >= off) v = s[t - off];
        __syncthreads();
        if (t >= off) s[t] += v;
        __syncthreads();
    }
    if (t < nb) bsums[t] = (t == 0) ? 0 : s[t - 1];
}

// writes off[i] (exclusive prefix) and end[i] = off[i] + cnt[i]
__global__ void scan_final(const int* __restrict__ cnt, const int* __restrict__ bsums,
                           int* __restrict__ off, int* __restrict__ end, int n) {
    __shared__ int s[256];
    int t = threadIdx.x;
    int i = blockIdx.x * 256 + t;
    int v = (i < n) ? cnt[i] : 0;
    s[t] = v;
    __syncthreads();
    for (int o = 1; o < 256; o <<= 1) {
        int u = 0;
        if (t >= o) u = s[t - o];
        __syncthreads();
        if (t >= o) s[t] += u;
        __syncthreads();
    }
    if (i < n) {
        int o0 = bsums[blockIdx.x] + s[t] - v;
        off[i] = o0;
        end[i] = o0 + v;
    }
}

// atomic-free scatter: position known from histo. Stores RAW weight bits.
__global__ void reorder_csr(const int* __restrict__ row, const int* __restrict__ col,
                            const float* __restrict__ w, const int* __restrict__ off,
                            const int* __restrict__ aux, uint2* __restrict__ csr, int E) {
    int e = blockIdx.x * blockDim.x + threadIdx.x;
    if (e >= E) return;
    int r = row[e];
    uint2 ent;
    ent.x = (unsigned int)col[e];
    ent.y = __float_as_uint(w[e]);
    csr[off[r] + aux[e]] = ent;
}

// per-node: wdeg = fill + segment sum of raw w -> dinv = rsqrt
__global__ void seg_dinv(const uint2* __restrict__ csr, const int* __restrict__ off,
                         const int* __restrict__ end, float* __restrict__ dinv,
                         int n, float fill) {
    int i = blockIdx.x * blockDim.x + threadIdx.x;
    if (i >= n) return;
    float d = fill;
    int s = off[i], e = end[i];
    for (int p = s; p < e; ++p) d += __uint_as_float(csr[p].y);
    dinv[i] = d > 0.0f ? rsqrtf(d) : 0.0f;
}

// fold dinv[r]*dinv[c] into stored weights (dinv is L2-resident, 400KB)
__global__ void norm_w(uint2* __restrict__ csr, const int* __restrict__ off,
                       const int* __restrict__ end, const float* __restrict__ dinv, int n) {
    int i = blockIdx.x * blockDim.x + threadIdx.x;
    if (i >= n) return;
    float di = dinv[i];
    int s = off[i], e = end[i];
    for (int p = s; p < e; ++p) {
        uint2 ent = csr[p];
        float wn = __uint_as_float(ent.y) * di * dinv[(int)ent.x];
        ((float*)csr)[2 * p + 1] = wn;
    }
}

// 8 nodes per wave; group g (8 lanes) owns node wave*8+g; lane q owns columns
// 8q..8q+7. 16 entries per iteration, all 16 gathers batched into static v[16]
// before any FMA. __launch_bounds__(256,4): 128-VGPR cap so v[16] stays in
// registers (default 1024-thread assumption capped at 64 VGPR -> spilled).
__global__ void __launch_bounds__(256, 4)
hop_g8(const unsigned short* __restrict__ xb, const float* __restrict__ dinv,
       const int* __restrict__ off, const int* __restrict__ end,
       const uint2* __restrict__ csr,
       unsigned short* __restrict__ outb, int n) {
    int t = blockIdx.x * blockDim.x + threadIdx.x;
    int wave = t >> 6;
    int lane = t & 63;
    int g = lane >> 3, q = lane & 7;
    int i = wave * 8 + g;
    bool active = i < n;
    int ii = active ? i : n - 1;

    const unsigned int* xw = (const unsigned int*)xb;
    float di = dinv[ii];
    float di2 = di * di;  // self-loop weight (fill=1): dinv^2
    uint4 sv = *(const uint4*)(xw + (long)ii * 32 + q * 4);
    float a0 = blo(sv.x) * di2, a1 = bhi(sv.x) * di2;
    float a2 = blo(sv.y) * di2, a3 = bhi(sv.y) * di2;
    float a4 = blo(sv.z) * di2, a5 = bhi(sv.z) * di2;
    float a6 = blo(sv.w) * di2, a7 = bhi(sv.w) * di2;

    int s = active ? off[ii] : 0;
    int e = active ? end[ii] : 0;

    for (int b = s; b < e; b += 16) {
        int i0 = b + q;     if (i0 >= e) i0 = e - 1;
        int i1 = b + 8 + q; if (i1 >= e) i1 = e - 1;
        uint2 e0 = csr[i0];
        uint2 e1 = csr[i1];
        uint4 v[16];
        float wv[16];
        #pragma unroll
        for (int j = 0; j < 16; ++j) {
            int srcl = g * 8 + (j & 7);
            int cb = __shfl((int)(j < 8 ? e0.x : e1.x), srcl, 64);
            float wj = __uint_as_float(__shfl((int)(j < 8 ? e0.y : e1.y), srcl, 64));
            if (b + j >= e) wj = 0.0f;
            wv[j] = wj;
            v[j] = make_uint4(0u, 0u, 0u, 0u);
            if (wj != 0.0f) v[j] = *(const uint4*)(xw + (long)cb * 32 + q * 4);
        }
        #pragma unroll
        for (int j = 0; j < 16; ++j) {
            float wj = wv[j];
            a0 += blo(v[j].x) * wj; a1 += bhi(v[j].x) * wj;
            a2 += blo(v[j].y) * wj; a3 += bhi(v[j].y) * wj;
            a4 += blo(v[j].z) * wj; a5 += bhi(v[j].z) * wj;
            a6 += blo(v[j].w) * wj; a7 += bhi(v[j].w) * wj;
        }
    }

    if (!active) return;
    uint4 o;
    o.x = packb(a0, a1); o.y = packb(a2, a3);
    o.z = packb(a4, a5); o.w = packb(a6, a7);
    *(uint4*)((unsigned int*)outb + (long)i * 32 + q * 4) = o;
}

// projection, shfl-free/LDS-free: lane l holds W[:,l] in 64 registers
// (launch_bounds lifts the 64-VGPR default cap so w[] stays in registers).
__global__ void __launch_bounds__(256, 4)
proj_reg(const unsigned short* __restrict__ h2b,
         const float* __restrict__ W, const float* __restrict__ bias,
         float* __restrict__ out, int n) {
    int lane = threadIdx.x & 63;
    int wave = (blockIdx.x * blockDim.x + threadIdx.x) >> 6;
    int nW = (gridDim.x * blockDim.x) >> 6;

    float w[64];
    #pragma unroll
    for (int k = 0; k < 64; ++k) w[k] = W[k * D + lane];
    float bl = bias[lane];

    const uint2* h2 = (const uint2*)h2b;  // 4 bf16 per uint2
    for (int r = wave; r < n; r += nW) {
        const uint2* hr = h2 + (long)r * 16;
        float y0 = bl, y1 = 0.f, y2 = 0.f, y3 = 0.f;
        #pragma unroll
        for (int c = 0; c < 16; ++c) {
            uint2 hv = hr[c];  // uniform across wave -> broadcast
            y0 += blo(hv.x) * w[4 * c + 0];
            y1 += bhi(hv.x) * w[4 * c + 1];
            y2 += blo(hv.y) * w[4 * c + 2];
            y3 += bhi(hv.y) * w[4 * c + 3];
        }
        out[(long)r * D + lane] = (y0 + y1) + (y2 + y3);
    }
}

extern "C" void kernel_launch(void* const* d_in, const int* in_sizes, int n_in,
                              void* d_out, int out_size, void* d_ws, size_t ws_size,
                              hipStream_t stream) {
    const float* x    = (const float*)d_in[0];
    const int*   ei   = (const int*)d_in[1];
    const float* ew   = (const float*)d_in[2];
    const float* W    = (const float*)d_in[3];
    const float* bias = (const float*)d_in[4];

    int n = in_sizes[0] / D;   // 100000
    int E = in_sizes[2];       // 1600000
    const int* row = ei;
    const int* col = ei + E;

    float* out = (float*)d_out;

    // workspace layout (4-byte units)
    float* dinv  = (float*)d_ws;                  // n
    int*   cnt   = (int*)(dinv + alignup(n));     // n
    int*   bsums = cnt + alignup(n);              // <=1024
    int*   off   = bsums + 1024;                  // n
    int*   endp  = off + alignup(n);              // n
    int*   aux   = endp + alignup(n);             // E
    uint2* csr   = (uint2*)(aux + alignup(E));    // E x 8B
    unsigned short* xb  = (unsigned short*)(csr + alignup(E)); // n*D bf16
    unsigned short* h1b = xb + (long)alignup(n) * D;           // n*D bf16
    unsigned short* h2b = h1b + (long)alignup(n) * D;          // n*D bf16

    const float fill = 1.0f;  // IMPROVED = False
    const int blk = 256;
    int nbN = (n + blk - 1) / blk;
    int nbE = (E + blk - 1) / blk;

    init_cnt<<<nbN, blk, 0, stream>>>(cnt, n);
    histo_pos<<<nbE, blk, 0, stream>>>(row, cnt, aux, E);

    long nElem = (long)n * D;
    int nbC = (int)((nElem / 4 + blk - 1) / blk);
    convert_bf16<<<nbC, blk, 0, stream>>>(x, xb, nElem);

    scan_block_sums<<<nbN, blk, 0, stream>>>(cnt, bsums, n);
    scan_bsums<<<1, 1024, 0, stream>>>(bsums, nbN);
    scan_final<<<nbN, blk, 0, stream>>>(cnt, bsums, off, endp, n);

    reorder_csr<<<nbE, blk, 0, stream>>>(row, col, ew, off, aux, csr, E);
    seg_dinv<<<nbN, blk, 0, stream>>>(csr, off, endp, dinv, n, fill);
    norm_w<<<nbN, blk, 0, stream>>>(csr, off, endp, dinv, n);

    int nWaves = (n + 7) / 8;
    int nbHop = (nWaves * 64 + blk - 1) / blk;
    hop_g8<<<nbHop, blk, 0, stream>>>(xb, dinv, off, endp, csr, h1b, n);
    hop_g8<<<nbHop, blk, 0, stream>>>(h1b, dinv, off, endp, csr, h2b, n);

    proj_reg<<<2048, blk, 0, stream>>>(h2b, W, bias, out, n);
}

// Round 11
// 251.290 us; speedup vs baseline: 1.6197x; 1.6197x over previous
//
#include <hip/hip_runtime.h>

#define D 64

static __host__ __device__ inline int alignup(int x) { return (x + 63) & ~63; }

__device__ inline float blo(unsigned int u) { return __uint_as_float(u << 16); }
__device__ inline float bhi(unsigned int u) { return __uint_as_float(u & 0xffff0000u); }
__device__ inline unsigned short f2b(float f) {
    unsigned int u = __float_as_uint(f);
    return (unsigned short)((u + 0x7FFFu + ((u >> 16) & 1u)) >> 16);
}
__device__ inline unsigned int packb(float lo, float hi) {
    return (unsigned int)f2b(lo) | ((unsigned int)f2b(hi) << 16);
}

__global__ void init_cnt(int* __restrict__ cnt, int n) {
    int i = blockIdx.x * blockDim.x + threadIdx.x;
    if (i < n) cnt[i] = 0;
}

// ONE atomic per edge: slot position within row + final counts.
__global__ void histo_pos(const int* __restrict__ row, int* __restrict__ cnt,
                          int* __restrict__ aux, int E) {
    int e = blockIdx.x * blockDim.x + threadIdx.x;
    if (e < E) aux[e] = atomicAdd(&cnt[row[e]], 1);
}

__global__ void convert_bf16(const float* __restrict__ x, unsigned short* __restrict__ xb, long nElem) {
    long t = (long)blockIdx.x * blockDim.x + threadIdx.x;
    long i = t * 4;
    if (i + 3 < nElem) {
        float4 v = *(const float4*)(x + i);
        ushort4 o;
        o.x = f2b(v.x); o.y = f2b(v.y); o.z = f2b(v.z); o.w = f2b(v.w);
        *(ushort4*)(xb + i) = o;
    } else {
        for (long k = i; k < nElem; ++k) xb[k] = f2b(x[k]);
    }
}

__global__ void scan_block_sums(const int* __restrict__ cnt, int* __restrict__ bsums, int n) {
    __shared__ int s[256];
    int t = threadIdx.x;
    int i = blockIdx.x * 256 + t;
    s[t] = (i < n) ? cnt[i] : 0;
    __syncthreads();
    for (int st = 128; st > 0; st >>= 1) {
        if (t < st) s[t] += s[t + st];
        __syncthreads();
    }
    if (t == 0) bsums[blockIdx.x] = s[0];
}

__global__ void scan_bsums(int* __restrict__ bsums, int nb) {
    __shared__ int s[1024];
    int t = threadIdx.x;
    s[t] = (t < nb) ? bsums[t] : 0;
    __syncthreads();
    for (int off = 1; off < 1024; off <<= 1) {
        int v = 0;
        if (t >= off) v = s[t - off];
        __syncthreads();
        if (t >= off) s[t] += v;
        __syncthreads();
    }
    if (t < nb) bsums[t] = (t == 0) ? 0 : s[t - 1];
}

// writes off[i] (exclusive prefix) and end[i] = off[i] + cnt[i]
__global__ void scan_final(const int* __restrict__ cnt, const int* __restrict__ bsums,
                           int* __restrict__ off, int* __restrict__ end, int n) {
    __shared__ int s[256];
    int t = threadIdx.x;
    int i = blockIdx.x * 256 + t;
    int v = (i < n) ? cnt[i] : 0;
    s[t] = v;
    __syncthreads();
    for (int o = 1; o < 256; o <<= 1) {
        int u = 0;
        if (t >= o) u = s[t - o];
        __syncthreads();
        if (t >= o) s[t] += u;
        __syncthreads();
    }
    if (i < n) {
        int o0 = bsums[blockIdx.x] + s[t] - v;
        off[i] = o0;
        end[i] = o0 + v;
    }
}

// atomic-free scatter: position known from histo. Stores RAW weight bits.
__global__ void reorder_csr(const int* __restrict__ row, const int* __restrict__ col,
                            const float* __restrict__ w, const int* __restrict__ off,
                            const int* __restrict__ aux, uint2* __restrict__ csr, int E) {
    int e = blockIdx.x * blockDim.x + threadIdx.x;
    if (e >= E) return;
    int r = row[e];
    uint2 ent;
    ent.x = (unsigned int)col[e];
    ent.y = __float_as_uint(w[e]);
    csr[off[r] + aux[e]] = ent;
}

// per-node: wdeg = fill + segment sum of raw w -> dinv = rsqrt
__global__ void seg_dinv(const uint2* __restrict__ csr, const int* __restrict__ off,
                         const int* __restrict__ end, float* __restrict__ dinv,
                         int n, float fill) {
    int i = blockIdx.x * blockDim.x + threadIdx.x;
    if (i >= n) return;
    float d = fill;
    int s = off[i], e = end[i];
    for (int p = s; p < e; ++p) d += __uint_as_float(csr[p].y);
    dinv[i] = d > 0.0f ? rsqrtf(d) : 0.0f;
}

// fold dinv[r]*dinv[c] into stored weights (dinv is L2-resident, 400KB)
__global__ void norm_w(uint2* __restrict__ csr, const int* __restrict__ off,
                       const int* __restrict__ end, const float* __restrict__ dinv, int n) {
    int i = blockIdx.x * blockDim.x + threadIdx.x;
    if (i >= n) return;
    float di = dinv[i];
    int s = off[i], e = end[i];
    for (int p = s; p < e; ++p) {
        uint2 ent = csr[p];
        float wn = __uint_as_float(ent.y) * di * dinv[(int)ent.x];
        ((float*)csr)[2 * p + 1] = wn;
    }
}

// 8 nodes per wave; group g (8 lanes) owns node wave*8+g; lane q owns columns
// 8q..8q+7. 16 entries per iteration, all 16 gathers batched into static v[16]
// before any FMA. amdgpu_waves_per_eu(2,4): register budget 256 so v[16]
// (64 VGPR) stays in registers (launch_bounds 2nd arg provably didn't lift
// the 64-VGPR default cap; direct LLVM attribute instead).
__global__ void __launch_bounds__(256)
__attribute__((amdgpu_waves_per_eu(2, 4)))
hop_g8(const unsigned short* __restrict__ xb, const float* __restrict__ dinv,
       const int* __restrict__ off, const int* __restrict__ end,
       const uint2* __restrict__ csr,
       unsigned short* __restrict__ outb, int n) {
    int t = blockIdx.x * blockDim.x + threadIdx.x;
    int wave = t >> 6;
    int lane = t & 63;
    int g = lane >> 3, q = lane & 7;
    int i = wave * 8 + g;
    bool active = i < n;
    int ii = active ? i : n - 1;

    const unsigned int* xw = (const unsigned int*)xb;
    float di = dinv[ii];
    float di2 = di * di;  // self-loop weight (fill=1): dinv^2
    uint4 sv = *(const uint4*)(xw + (long)ii * 32 + q * 4);
    float a0 = blo(sv.x) * di2, a1 = bhi(sv.x) * di2;
    float a2 = blo(sv.y) * di2, a3 = bhi(sv.y) * di2;
    float a4 = blo(sv.z) * di2, a5 = bhi(sv.z) * di2;
    float a6 = blo(sv.w) * di2, a7 = bhi(sv.w) * di2;

    int s = active ? off[ii] : 0;
    int e = active ? end[ii] : 0;

    for (int b = s; b < e; b += 16) {
        int i0 = b + q;     if (i0 >= e) i0 = e - 1;
        int i1 = b + 8 + q; if (i1 >= e) i1 = e - 1;
        uint2 e0 = csr[i0];
        uint2 e1 = csr[i1];
        uint4 v[16];
        float wv[16];
        #pragma unroll
        for (int j = 0; j < 16; ++j) {
            int srcl = g * 8 + (j & 7);
            int cb = __shfl((int)(j < 8 ? e0.x : e1.x), srcl, 64);
            float wj = __uint_as_float(__shfl((int)(j < 8 ? e0.y : e1.y), srcl, 64));
            if (b + j >= e) wj = 0.0f;
            wv[j] = wj;
            v[j] = make_uint4(0u, 0u, 0u, 0u);
            if (wj != 0.0f) v[j] = *(const uint4*)(xw + (long)cb * 32 + q * 4);
        }
        #pragma unroll
        for (int j = 0; j < 16; ++j) {
            float wj = wv[j];
            a0 += blo(v[j].x) * wj; a1 += bhi(v[j].x) * wj;
            a2 += blo(v[j].y) * wj; a3 += bhi(v[j].y) * wj;
            a4 += blo(v[j].z) * wj; a5 += bhi(v[j].z) * wj;
            a6 += blo(v[j].w) * wj; a7 += bhi(v[j].w) * wj;
        }
    }

    if (!active) return;
    uint4 o;
    o.x = packb(a0, a1); o.y = packb(a2, a3);
    o.z = packb(a4, a5); o.w = packb(a6, a7);
    *(uint4*)((unsigned int*)outb + (long)i * 32 + q * 4) = o;
}

// projection: lane l holds W[:,l] as 32 bf16-PAIR registers (~48 VGPR total,
// fits the 64-VGPR cap -> cannot spill). Per row: 16 uniform-address uint2
// loads (wave-broadcast bf16 h-row), unpack+FMA, one coalesced f32 store.
__global__ void __launch_bounds__(256)
proj_regb(const unsigned short* __restrict__ h2b,
          const float* __restrict__ W, const float* __restrict__ bias,
          float* __restrict__ out, int n) {
    int lane = threadIdx.x & 63;
    int wave = (blockIdx.x * blockDim.x + threadIdx.x) >> 6;
    int nW = (gridDim.x * blockDim.x) >> 6;

    unsigned int wb[32];  // bf16 pairs: wb[p] = {W[2p][lane], W[2p+1][lane]}
    #pragma unroll
    for (int p = 0; p < 32; ++p) {
        wb[p] = packb(W[(2 * p) * D + lane], W[(2 * p + 1) * D + lane]);
    }
    float bl = bias[lane];

    const uint2* h2 = (const uint2*)h2b;  // 4 bf16 per uint2
    for (int r = wave; r < n; r += nW) {
        const uint2* hr = h2 + (long)r * 16;
        float y0 = bl, y1 = 0.f, y2 = 0.f, y3 = 0.f;
        #pragma unroll
        for (int c = 0; c < 16; ++c) {
            uint2 hv = hr[c];             // k = 4c .. 4c+3 (uniform -> broadcast)
            unsigned int wp0 = wb[2 * c];      // k=4c, 4c+1
            unsigned int wp1 = wb[2 * c + 1];  // k=4c+2, 4c+3
            y0 += blo(hv.x) * blo(wp0);
            y1 += bhi(hv.x) * bhi(wp0);
            y2 += blo(hv.y) * blo(wp1);
            y3 += bhi(hv.y) * bhi(wp1);
        }
        out[(long)r * D + lane] = (y0 + y1) + (y2 + y3);
    }
}

extern "C" void kernel_launch(void* const* d_in, const int* in_sizes, int n_in,
                              void* d_out, int out_size, void* d_ws, size_t ws_size,
                              hipStream_t stream) {
    const float* x    = (const float*)d_in[0];
    const int*   ei   = (const int*)d_in[1];
    const float* ew   = (const float*)d_in[2];
    const float* W    = (const float*)d_in[3];
    const float* bias = (const float*)d_in[4];

    int n = in_sizes[0] / D;   // 100000
    int E = in_sizes[2];       // 1600000
    const int* row = ei;
    const int* col = ei + E;

    float* out = (float*)d_out;

    // workspace layout (4-byte units)
    float* dinv  = (float*)d_ws;                  // n
    int*   cnt   = (int*)(dinv + alignup(n));     // n
    int*   bsums = cnt + alignup(n);              // <=1024
    int*   off   = bsums + 1024;                  // n
    int*   endp  = off + alignup(n);              // n
    int*   aux   = endp + alignup(n);             // E
    uint2* csr   = (uint2*)(aux + alignup(E));    // E x 8B
    unsigned short* xb  = (unsigned short*)(csr + alignup(E)); // n*D bf16
    unsigned short* h1b = xb + (long)alignup(n) * D;           // n*D bf16
    unsigned short* h2b = h1b + (long)alignup(n) * D;          // n*D bf16

    const float fill = 1.0f;  // IMPROVED = False
    const int blk = 256;
    int nbN = (n + blk - 1) / blk;
    int nbE = (E + blk - 1) / blk;

    init_cnt<<<nbN, blk, 0, stream>>>(cnt, n);
    histo_pos<<<nbE, blk, 0, stream>>>(row, cnt, aux, E);

    long nElem = (long)n * D;
    int nbC = (int)((nElem / 4 + blk - 1) / blk);
    convert_bf16<<<nbC, blk, 0, stream>>>(x, xb, nElem);

    scan_block_sums<<<nbN, blk, 0, stream>>>(cnt, bsums, n);
    scan_bsums<<<1, 1024, 0, stream>>>(bsums, nbN);
    scan_final<<<nbN, blk, 0, stream>>>(cnt, bsums, off, endp, n);

    reorder_csr<<<nbE, blk, 0, stream>>>(row, col, ew, off, aux, csr, E);
    seg_dinv<<<nbN, blk, 0, stream>>>(csr, off, endp, dinv, n, fill);
    norm_w<<<nbN, blk, 0, stream>>>(csr, off, endp, dinv, n);

    int nWaves = (n + 7) / 8;
    int nbHop = (nWaves * 64 + blk - 1) / blk;
    hop_g8<<<nbHop, blk, 0, stream>>>(xb, dinv, off, endp, csr, h1b, n);
    hop_g8<<<nbHop, blk, 0, stream>>>(h1b, dinv, off, endp, csr, h2b, n);

    proj_regb<<<1024, blk, 0, stream>>>(h2b, W, bias, out, n);
}

// Round 12
// 209.614 us; speedup vs baseline: 1.9417x; 1.1988x over previous
//
#include <hip/hip_runtime.h>

#define D 64

static __host__ __device__ inline int alignup(int x) { return (x + 63) & ~63; }

__device__ inline float blo(unsigned int u) { return __uint_as_float(u << 16); }
__device__ inline float bhi(unsigned int u) { return __uint_as_float(u & 0xffff0000u); }
__device__ inline unsigned short f2b(float f) {
    unsigned int u = __float_as_uint(f);
    return (unsigned short)((u + 0x7FFFu + ((u >> 16) & 1u)) >> 16);
}
__device__ inline unsigned int packb(float lo, float hi) {
    return (unsigned int)f2b(lo) | ((unsigned int)f2b(hi) << 16);
}

__global__ void convert_bf16(const float* __restrict__ x, unsigned short* __restrict__ xb, long nElem) {
    long t = (long)blockIdx.x * blockDim.x + threadIdx.x;
    long i = t * 4;
    if (i + 3 < nElem) {
        float4 v = *(const float4*)(x + i);
        ushort4 o;
        o.x = f2b(v.x); o.y = f2b(v.y); o.z = f2b(v.z); o.w = f2b(v.w);
        *(ushort4*)(xb + i) = o;
    } else {
        for (long k = i; k < nElem; ++k) xb[k] = f2b(x[k]);
    }
}

// ---------- bucket-sort CSR build: LDS atomics only, ZERO global atomics ----
// bucket = row >> 8 (256 rows/bucket). NB <= 512 (n <= 131072).

// Pass A: per-block bucket histogram (LDS), write bhist[bucket][block]
__global__ void countA(const int* __restrict__ row, int* __restrict__ bhist,
                       int E, int chunk, int NB) {
    __shared__ int h[512];
    int b = blockIdx.x;
    for (int k = threadIdx.x; k < NB; k += blockDim.x) h[k] = 0;
    __syncthreads();
    int s = b * chunk, e = min(s + chunk, E);
    for (int p = s + (int)threadIdx.x; p < e; p += blockDim.x)
        atomicAdd(&h[row[p] >> 8], 1);
    __syncthreads();
    for (int k = threadIdx.x; k < NB; k += blockDim.x)
        bhist[k * 256 + b] = h[k];
}

// Pass A2: per-bucket exclusive scan over the 256 blocks; bucket totals.
__global__ void scanA(int* __restrict__ bhist, int* __restrict__ bcnt, int NB) {
    __shared__ int s[256];
    int k = blockIdx.x;
    int t = threadIdx.x;
    int v = bhist[k * 256 + t];
    s[t] = v;
    __syncthreads();
    for (int o = 1; o < 256; o <<= 1) {
        int u = (t >= o) ? s[t - o] : 0;
        __syncthreads();
        if (t >= o) s[t] += u;
        __syncthreads();
    }
    bhist[k * 256 + t] = s[t] - v;  // exclusive within bucket
    if (t == 255) bcnt[k] = s[t];
}

// Pass A3: exclusive scan of bucket totals -> bucket offsets (NB <= 512)
__global__ void scan_boff(const int* __restrict__ bcnt, int* __restrict__ boff, int nb) {
    __shared__ int s[512];
    int t = threadIdx.x;
    s[t] = (t < nb) ? bcnt[t] : 0;
    __syncthreads();
    for (int o = 1; o < 512; o <<= 1) {
        int v = (t >= o) ? s[t - o] : 0;
        __syncthreads();
        if (t >= o) s[t] += v;
        __syncthreads();
    }
    if (t < nb) boff[t] = (t == 0) ? 0 : s[t - 1];
}

// Pass B: scatter edges into bucket-sorted ebuf via LDS cursors.
// ebuf entry: .x = (rowloc<<24) | col  (col < 2^24), .y = raw weight bits
__global__ void scatterB(const int* __restrict__ row, const int* __restrict__ col,
                         const float* __restrict__ w, const int* __restrict__ bhist,
                         const int* __restrict__ boff, uint2* __restrict__ ebuf,
                         int E, int chunk, int NB) {
    __shared__ int cur[512];
    int b = blockIdx.x;
    for (int k = threadIdx.x; k < NB; k += blockDim.x)
        cur[k] = boff[k] + bhist[k * 256 + b];
    __syncthreads();
    int s = b * chunk, e = min(s + chunk, E);
    for (int p = s + (int)threadIdx.x; p < e; p += blockDim.x) {
        int r = row[p];
        int bkt = r >> 8;
        int pos = atomicAdd(&cur[bkt], 1);
        ebuf[pos] = make_uint2(((unsigned)(r & 255) << 24) | (unsigned)col[p],
                               __float_as_uint(w[p]));
    }
}

// Pass C1: per-bucket fine count (256 LDS counters) -> cnt[row]
__global__ void fineC1(const uint2* __restrict__ ebuf, const int* __restrict__ boff,
                       const int* __restrict__ bcnt, int* __restrict__ cnt, int n) {
    __shared__ int c2[256];
    int k = blockIdx.x;
    c2[threadIdx.x] = 0;
    __syncthreads();
    int s = boff[k], e = s + bcnt[k];
    for (int p = s + (int)threadIdx.x; p < e; p += blockDim.x)
        atomicAdd(&c2[ebuf[p].x >> 24], 1);
    __syncthreads();
    int r = k * 256 + threadIdx.x;
    if (r < n) cnt[r] = c2[threadIdx.x];
}

// Pass C2: re-derive within-row position via LDS atomics, place into CSR.
__global__ void placeC2(const uint2* __restrict__ ebuf, const int* __restrict__ boff,
                        const int* __restrict__ bcnt, const int* __restrict__ off,
                        uint2* __restrict__ csr, int n) {
    __shared__ int c2[256];
    int k = blockIdx.x;
    c2[threadIdx.x] = 0;
    __syncthreads();
    int s = boff[k], e = s + bcnt[k];
    for (int p = s + (int)threadIdx.x; p < e; p += blockDim.x) {
        uint2 ent = ebuf[p];
        int rl = (int)(ent.x >> 24);
        int pos = atomicAdd(&c2[rl], 1);
        int r = k * 256 + rl;
        csr[off[r] + pos] = make_uint2(ent.x & 0xFFFFFFu, ent.y);
    }
}

// ---------- scans over n (exclusive prefix of cnt -> off, end) --------------
__global__ void scan_block_sums(const int* __restrict__ cnt, int* __restrict__ bsums, int n) {
    __shared__ int s[256];
    int t = threadIdx.x;
    int i = blockIdx.x * 256 + t;
    s[t] = (i < n) ? cnt[i] : 0;
    __syncthreads();
    for (int st = 128; st > 0; st >>= 1) {
        if (t < st) s[t] += s[t + st];
        __syncthreads();
    }
    if (t == 0) bsums[blockIdx.x] = s[0];
}

__global__ void scan_bsums(int* __restrict__ bsums, int nb) {
    __shared__ int s[1024];
    int t = threadIdx.x;
    s[t] = (t < nb) ? bsums[t] : 0;
    __syncthreads();
    for (int off = 1; off < 1024; off <<= 1) {
        int v = 0;
        if (t >= off) v = s[t - off];
        __syncthreads();
        if (t >= off) s[t] += v;
        __syncthreads();
    }
    if (t < nb) bsums[t] = (t == 0) ? 0 : s[t - 1];
}

__global__ void scan_final(const int* __restrict__ cnt, const int* __restrict__ bsums,
                           int* __restrict__ off, int* __restrict__ end, int n) {
    __shared__ int s[256];
    int t = threadIdx.x;
    int i = blockIdx.x * 256 + t;
    int v = (i < n) ? cnt[i] : 0;
    s[t] = v;
    __syncthreads();
    for (int o = 1; o < 256; o <<= 1) {
        int u = 0;
        if (t >= o) u = s[t - o];
        __syncthreads();
        if (t >= o) s[t] += u;
        __syncthreads();
    }
    if (i < n) {
        int o0 = bsums[blockIdx.x] + s[t] - v;
        off[i] = o0;
        end[i] = o0 + v;
    }
}

// per-node: wdeg = fill + segment sum of raw w -> dinv = rsqrt
__global__ void seg_dinv(const uint2* __restrict__ csr, const int* __restrict__ off,
                         const int* __restrict__ end, float* __restrict__ dinv,
                         int n, float fill) {
    int i = blockIdx.x * blockDim.x + threadIdx.x;
    if (i >= n) return;
    float d = fill;
    int s = off[i], e = end[i];
    for (int p = s; p < e; ++p) d += __uint_as_float(csr[p].y);
    dinv[i] = d > 0.0f ? rsqrtf(d) : 0.0f;
}

// fold dinv[r]*dinv[c] into stored weights
__global__ void norm_w(uint2* __restrict__ csr, const int* __restrict__ off,
                       const int* __restrict__ end, const float* __restrict__ dinv, int n) {
    int i = blockIdx.x * blockDim.x + threadIdx.x;
    if (i >= n) return;
    float di = dinv[i];
    int s = off[i], e = end[i];
    for (int p = s; p < e; ++p) {
        uint2 ent = csr[p];
        float wn = __uint_as_float(ent.y) * di * dinv[(int)ent.x];
        ((float*)csr)[2 * p + 1] = wn;
    }
}

// 8 nodes per wave; group g (8 lanes) owns node wave*8+g; lane q owns columns
// 8q..8q+7. 16 entries per iteration, all gathers batched into static v[16].
__global__ void __launch_bounds__(256)
__attribute__((amdgpu_waves_per_eu(2, 4)))
hop_g8(const unsigned short* __restrict__ xb, const float* __restrict__ dinv,
       const int* __restrict__ off, const int* __restrict__ end,
       const uint2* __restrict__ csr,
       unsigned short* __restrict__ outb, int n) {
    int t = blockIdx.x * blockDim.x + threadIdx.x;
    int wave = t >> 6;
    int lane = t & 63;
    int g = lane >> 3, q = lane & 7;
    int i = wave * 8 + g;
    bool active = i < n;
    int ii = active ? i : n - 1;

    const unsigned int* xw = (const unsigned int*)xb;
    float di = dinv[ii];
    float di2 = di * di;  // self-loop weight (fill=1): dinv^2
    uint4 sv = *(const uint4*)(xw + (long)ii * 32 + q * 4);
    float a0 = blo(sv.x) * di2, a1 = bhi(sv.x) * di2;
    float a2 = blo(sv.y) * di2, a3 = bhi(sv.y) * di2;
    float a4 = blo(sv.z) * di2, a5 = bhi(sv.z) * di2;
    float a6 = blo(sv.w) * di2, a7 = bhi(sv.w) * di2;

    int s = active ? off[ii] : 0;
    int e = active ? end[ii] : 0;

    for (int b = s; b < e; b += 16) {
        int i0 = b + q;     if (i0 >= e) i0 = e - 1;
        int i1 = b + 8 + q; if (i1 >= e) i1 = e - 1;
        uint2 e0 = csr[i0];
        uint2 e1 = csr[i1];
        uint4 v[16];
        float wv[16];
        #pragma unroll
        for (int j = 0; j < 16; ++j) {
            int srcl = g * 8 + (j & 7);
            int cb = __shfl((int)(j < 8 ? e0.x : e1.x), srcl, 64);
            float wj = __uint_as_float(__shfl((int)(j < 8 ? e0.y : e1.y), srcl, 64));
            if (b + j >= e) wj = 0.0f;
            wv[j] = wj;
            v[j] = make_uint4(0u, 0u, 0u, 0u);
            if (wj != 0.0f) v[j] = *(const uint4*)(xw + (long)cb * 32 + q * 4);
        }
        #pragma unroll
        for (int j = 0; j < 16; ++j) {
            float wj = wv[j];
            a0 += blo(v[j].x) * wj; a1 += bhi(v[j].x) * wj;
            a2 += blo(v[j].y) * wj; a3 += bhi(v[j].y) * wj;
            a4 += blo(v[j].z) * wj; a5 += bhi(v[j].z) * wj;
            a6 += blo(v[j].w) * wj; a7 += bhi(v[j].w) * wj;
        }
    }

    if (!active) return;
    uint4 o;
    o.x = packb(a0, a1); o.y = packb(a2, a3);
    o.z = packb(a4, a5); o.w = packb(a6, a7);
    *(uint4*)((unsigned int*)outb + (long)i * 32 + q * 4) = o;
}

// projection: lane l holds W[:,l] as 32 bf16-pair registers (~48 VGPR, no spill)
__global__ void __launch_bounds__(256)
proj_regb(const unsigned short* __restrict__ h2b,
          const float* __restrict__ W, const float* __restrict__ bias,
          float* __restrict__ out, int n) {
    int lane = threadIdx.x & 63;
    int wave = (blockIdx.x * blockDim.x + threadIdx.x) >> 6;
    int nW = (gridDim.x * blockDim.x) >> 6;

    unsigned int wb[32];
    #pragma unroll
    for (int p = 0; p < 32; ++p) {
        wb[p] = packb(W[(2 * p) * D + lane], W[(2 * p + 1) * D + lane]);
    }
    float bl = bias[lane];

    const uint2* h2 = (const uint2*)h2b;
    for (int r = wave; r < n; r += nW) {
        const uint2* hr = h2 + (long)r * 16;
        float y0 = bl, y1 = 0.f, y2 = 0.f, y3 = 0.f;
        #pragma unroll
        for (int c = 0; c < 16; ++c) {
            uint2 hv = hr[c];
            unsigned int wp0 = wb[2 * c];
            unsigned int wp1 = wb[2 * c + 1];
            y0 += blo(hv.x) * blo(wp0);
            y1 += bhi(hv.x) * bhi(wp0);
            y2 += blo(hv.y) * blo(wp1);
            y3 += bhi(hv.y) * bhi(wp1);
        }
        out[(long)r * D + lane] = (y0 + y1) + (y2 + y3);
    }
}

extern "C" void kernel_launch(void* const* d_in, const int* in_sizes, int n_in,
                              void* d_out, int out_size, void* d_ws, size_t ws_size,
                              hipStream_t stream) {
    const float* x    = (const float*)d_in[0];
    const int*   ei   = (const int*)d_in[1];
    const float* ew   = (const float*)d_in[2];
    const float* W    = (const float*)d_in[3];
    const float* bias = (const float*)d_in[4];

    int n = in_sizes[0] / D;   // 100000
    int E = in_sizes[2];       // 1600000
    const int* row = ei;
    const int* col = ei + E;

    float* out = (float*)d_out;

    const int NB = (n + 255) >> 8;        // 391 buckets (<=512 for n<=131072)
    const int BA = 256;                    // blocks in bucket passes
    int chunk = (E + BA - 1) / BA;

    // workspace layout (4-byte units)
    float* dinv  = (float*)d_ws;                  // n
    int*   cnt   = (int*)(dinv + alignup(n));     // n
    int*   bsums = cnt + alignup(n);              // 1024
    int*   off   = bsums + 1024;                  // n
    int*   endp  = off + alignup(n);              // n
    int*   bcnt  = endp + alignup(n);             // 512
    int*   boff  = bcnt + 512;                    // 512
    int*   bhist = boff + 512;                    // NB*256 (<=512*256)
    uint2* csr   = (uint2*)(bhist + alignup(NB * 256)); // E x 8B
    unsigned short* xb  = (unsigned short*)(csr + alignup(E)); // n*D bf16
    unsigned short* h1b = xb + (long)alignup(n) * D;           // n*D bf16
    unsigned short* h2b = h1b + (long)alignup(n) * D;          // n*D bf16
    uint2* ebuf = (uint2*)h2b;  // aliases h2b: consumed before hop2 writes it
                                 // (E*8 bytes == n*D*2 bytes == 12.8 MB)

    const float fill = 1.0f;  // IMPROVED = False
    const int blk = 256;
    int nbN = (n + blk - 1) / blk;

    long nElem = (long)n * D;
    int nbC = (int)((nElem / 4 + blk - 1) / blk);
    convert_bf16<<<nbC, blk, 0, stream>>>(x, xb, nElem);

    // bucket-sort CSR build (LDS atomics only)
    countA<<<BA, 256, 0, stream>>>(row, bhist, E, chunk, NB);
    scanA<<<NB, 256, 0, stream>>>(bhist, bcnt, NB);
    scan_boff<<<1, 512, 0, stream>>>(bcnt, boff, NB);
    scatterB<<<BA, 256, 0, stream>>>(row, col, ew, bhist, boff, ebuf, E, chunk, NB);
    fineC1<<<NB, 256, 0, stream>>>(ebuf, boff, bcnt, cnt, n);
    scan_block_sums<<<nbN, blk, 0, stream>>>(cnt, bsums, n);
    scan_bsums<<<1, 1024, 0, stream>>>(bsums, nbN);
    scan_final<<<nbN, blk, 0, stream>>>(cnt, bsums, off, endp, n);
    placeC2<<<NB, 256, 0, stream>>>(ebuf, boff, bcnt, off, csr, n);

    seg_dinv<<<nbN, blk, 0, stream>>>(csr, off, endp, dinv, n, fill);
    norm_w<<<nbN, blk, 0, stream>>>(csr, off, endp, dinv, n);

    int nWaves = (n + 7) / 8;
    int nbHop = (nWaves * 64 + blk - 1) / blk;
    hop_g8<<<nbHop, blk, 0, stream>>>(xb, dinv, off, endp, csr, h1b, n);
    hop_g8<<<nbHop, blk, 0, stream>>>(h1b, dinv, off, endp, csr, h2b, n);

    proj_regb<<<1024, blk, 0, stream>>>(h2b, W, bias, out, n);
}

// Round 13
// 205.801 us; speedup vs baseline: 1.9777x; 1.0185x over previous
//
#include <hip/hip_runtime.h>

#define D 64

static __host__ __device__ inline int alignup(int x) { return (x + 63) & ~63; }

__device__ inline float blo(unsigned int u) { return __uint_as_float(u << 16); }
__device__ inline float bhi(unsigned int u) { return __uint_as_float(u & 0xffff0000u); }
__device__ inline unsigned short f2b(float f) {
    unsigned int u = __float_as_uint(f);
    return (unsigned short)((u + 0x7FFFu + ((u >> 16) & 1u)) >> 16);
}
__device__ inline unsigned int packb(float lo, float hi) {
    return (unsigned int)f2b(lo) | ((unsigned int)f2b(hi) << 16);
}

__global__ void convert_bf16(const float* __restrict__ x, unsigned short* __restrict__ xb, long nElem) {
    long t = (long)blockIdx.x * blockDim.x + threadIdx.x;
    long i = t * 4;
    if (i + 3 < nElem) {
        float4 v = *(const float4*)(x + i);
        ushort4 o;
        o.x = f2b(v.x); o.y = f2b(v.y); o.z = f2b(v.z); o.w = f2b(v.w);
        *(ushort4*)(xb + i) = o;
    } else {
        for (long k = i; k < nElem; ++k) xb[k] = f2b(x[k]);
    }
}

// ---------- bucket-sort CSR build: LDS atomics only, ZERO global atomics ----
// bucket = row >> 8 (256 rows/bucket). NB <= 512 (n <= 131072).

__global__ void countA(const int* __restrict__ row, int* __restrict__ bhist,
                       int E, int chunk, int NB) {
    __shared__ int h[512];
    int b = blockIdx.x;
    for (int k = threadIdx.x; k < NB; k += blockDim.x) h[k] = 0;
    __syncthreads();
    int s = b * chunk, e = min(s + chunk, E);
    for (int p = s + (int)threadIdx.x; p < e; p += blockDim.x)
        atomicAdd(&h[row[p] >> 8], 1);
    __syncthreads();
    for (int k = threadIdx.x; k < NB; k += blockDim.x)
        bhist[k * 256 + b] = h[k];
}

__global__ void scanA(int* __restrict__ bhist, int* __restrict__ bcnt, int NB) {
    __shared__ int s[256];
    int k = blockIdx.x;
    int t = threadIdx.x;
    int v = bhist[k * 256 + t];
    s[t] = v;
    __syncthreads();
    for (int o = 1; o < 256; o <<= 1) {
        int u = (t >= o) ? s[t - o] : 0;
        __syncthreads();
        if (t >= o) s[t] += u;
        __syncthreads();
    }
    bhist[k * 256 + t] = s[t] - v;  // exclusive within bucket
    if (t == 255) bcnt[k] = s[t];
}

__global__ void scan_boff(const int* __restrict__ bcnt, int* __restrict__ boff, int nb) {
    __shared__ int s[512];
    int t = threadIdx.x;
    s[t] = (t < nb) ? bcnt[t] : 0;
    __syncthreads();
    for (int o = 1; o < 512; o <<= 1) {
        int v = (t >= o) ? s[t - o] : 0;
        __syncthreads();
        if (t >= o) s[t] += v;
        __syncthreads();
    }
    if (t < nb) boff[t] = (t == 0) ? 0 : s[t - 1];
}

// ebuf entry: .x = (rowloc<<24) | col  (col < 2^24), .y = raw weight bits
__global__ void scatterB(const int* __restrict__ row, const int* __restrict__ col,
                         const float* __restrict__ w, const int* __restrict__ bhist,
                         const int* __restrict__ boff, uint2* __restrict__ ebuf,
                         int E, int chunk, int NB) {
    __shared__ int cur[512];
    int b = blockIdx.x;
    for (int k = threadIdx.x; k < NB; k += blockDim.x)
        cur[k] = boff[k] + bhist[k * 256 + b];
    __syncthreads();
    int s = b * chunk, e = min(s + chunk, E);
    for (int p = s + (int)threadIdx.x; p < e; p += blockDim.x) {
        int r = row[p];
        int bkt = r >> 8;
        int pos = atomicAdd(&cur[bkt], 1);
        ebuf[pos] = make_uint2(((unsigned)(r & 255) << 24) | (unsigned)col[p],
                               __float_as_uint(w[p]));
    }
}

__global__ void fineC1(const uint2* __restrict__ ebuf, const int* __restrict__ boff,
                       const int* __restrict__ bcnt, int* __restrict__ cnt, int n) {
    __shared__ int c2[256];
    int k = blockIdx.x;
    c2[threadIdx.x] = 0;
    __syncthreads();
    int s = boff[k], e = s + bcnt[k];
    for (int p = s + (int)threadIdx.x; p < e; p += blockDim.x)
        atomicAdd(&c2[ebuf[p].x >> 24], 1);
    __syncthreads();
    int r = k * 256 + threadIdx.x;
    if (r < n) cnt[r] = c2[threadIdx.x];
}

__global__ void placeC2(const uint2* __restrict__ ebuf, const int* __restrict__ boff,
                        const int* __restrict__ bcnt, const int* __restrict__ off,
                        uint2* __restrict__ csr, int n) {
    __shared__ int c2[256];
    int k = blockIdx.x;
    c2[threadIdx.x] = 0;
    __syncthreads();
    int s = boff[k], e = s + bcnt[k];
    for (int p = s + (int)threadIdx.x; p < e; p += blockDim.x) {
        uint2 ent = ebuf[p];
        int rl = (int)(ent.x >> 24);
        int pos = atomicAdd(&c2[rl], 1);
        int r = k * 256 + rl;
        csr[off[r] + pos] = make_uint2(ent.x & 0xFFFFFFu, ent.y);
    }
}

// ---------- scans over n (exclusive prefix of cnt -> off, end) --------------
__global__ void scan_block_sums(const int* __restrict__ cnt, int* __restrict__ bsums, int n) {
    __shared__ int s[256];
    int t = threadIdx.x;
    int i = blockIdx.x * 256 + t;
    s[t] = (i < n) ? cnt[i] : 0;
    __syncthreads();
    for (int st = 128; st > 0; st >>= 1) {
        if (t < st) s[t] += s[t + st];
        __syncthreads();
    }
    if (t == 0) bsums[blockIdx.x] = s[0];
}

__global__ void scan_bsums(int* __restrict__ bsums, int nb) {
    __shared__ int s[1024];
    int t = threadIdx.x;
    s[t] = (t < nb) ? bsums[t] : 0;
    __syncthreads();
    for (int off = 1; off < 1024; off <<= 1) {
        int v = 0;
        if (t >= off) v = s[t - off];
        __syncthreads();
        if (t >= off) s[t] += v;
        __syncthreads();
    }
    if (t < nb) bsums[t] = (t == 0) ? 0 : s[t - 1];
}

__global__ void scan_final(const int* __restrict__ cnt, const int* __restrict__ bsums,
                           int* __restrict__ off, int* __restrict__ end, int n) {
    __shared__ int s[256];
    int t = threadIdx.x;
    int i = blockIdx.x * 256 + t;
    int v = (i < n) ? cnt[i] : 0;
    s[t] = v;
    __syncthreads();
    for (int o = 1; o < 256; o <<= 1) {
        int u = 0;
        if (t >= o) u = s[t - o];
        __syncthreads();
        if (t >= o) s[t] += u;
        __syncthreads();
    }
    if (i < n) {
        int o0 = bsums[blockIdx.x] + s[t] - v;
        off[i] = o0;
        end[i] = o0 + v;
    }
}

__global__ void seg_dinv(const uint2* __restrict__ csr, const int* __restrict__ off,
                         const int* __restrict__ end, float* __restrict__ dinv,
                         int n, float fill) {
    int i = blockIdx.x * blockDim.x + threadIdx.x;
    if (i >= n) return;
    float d = fill;
    int s = off[i], e = end[i];
    for (int p = s; p < e; ++p) d += __uint_as_float(csr[p].y);
    dinv[i] = d > 0.0f ? rsqrtf(d) : 0.0f;
}

__global__ void norm_w(uint2* __restrict__ csr, const int* __restrict__ off,
                       const int* __restrict__ end, const float* __restrict__ dinv, int n) {
    int i = blockIdx.x * blockDim.x + threadIdx.x;
    if (i >= n) return;
    float di = dinv[i];
    int s = off[i], e = end[i];
    for (int p = s; p < e; ++p) {
        uint2 ent = csr[p];
        float wn = __uint_as_float(ent.y) * di * dinv[(int)ent.x];
        ((float*)csr)[2 * p + 1] = wn;
    }
}

// 8 nodes per wave; group g (8 lanes) owns node wave*8+g; lane q owns columns
// 8q..8q+7. 16 entries per iteration, all gathers batched into static v[16].
__global__ void __launch_bounds__(256)
__attribute__((amdgpu_waves_per_eu(2, 4)))
hop_g8(const unsigned short* __restrict__ xb, const float* __restrict__ dinv,
       const int* __restrict__ off, const int* __restrict__ end,
       const uint2* __restrict__ csr,
       unsigned short* __restrict__ outb, int n) {
    int t = blockIdx.x * blockDim.x + threadIdx.x;
    int wave = t >> 6;
    int lane = t & 63;
    int g = lane >> 3, q = lane & 7;
    int i = wave * 8 + g;
    bool active = i < n;
    int ii = active ? i : n - 1;

    const unsigned int* xw = (const unsigned int*)xb;
    float di = dinv[ii];
    float di2 = di * di;  // self-loop weight (fill=1): dinv^2
    uint4 sv = *(const uint4*)(xw + (long)ii * 32 + q * 4);
    float a0 = blo(sv.x) * di2, a1 = bhi(sv.x) * di2;
    float a2 = blo(sv.y) * di2, a3 = bhi(sv.y) * di2;
    float a4 = blo(sv.z) * di2, a5 = bhi(sv.z) * di2;
    float a6 = blo(sv.w) * di2, a7 = bhi(sv.w) * di2;

    int s = active ? off[ii] : 0;
    int e = active ? end[ii] : 0;

    for (int b = s; b < e; b += 16) {
        int i0 = b + q;     if (i0 >= e) i0 = e - 1;
        int i1 = b + 8 + q; if (i1 >= e) i1 = e - 1;
        uint2 e0 = csr[i0];
        uint2 e1 = csr[i1];
        uint4 v[16];
        float wv[16];
        #pragma unroll
        for (int j = 0; j < 16; ++j) {
            int srcl = g * 8 + (j & 7);
            int cb = __shfl((int)(j < 8 ? e0.x : e1.x), srcl, 64);
            float wj = __uint_as_float(__shfl((int)(j < 8 ? e0.y : e1.y), srcl, 64));
            if (b + j >= e) wj = 0.0f;
            wv[j] = wj;
            v[j] = make_uint4(0u, 0u, 0u, 0u);
            if (wj != 0.0f) v[j] = *(const uint4*)(xw + (long)cb * 32 + q * 4);
        }
        #pragma unroll
        for (int j = 0; j < 16; ++j) {
            float wj = wv[j];
            a0 += blo(v[j].x) * wj; a1 += bhi(v[j].x) * wj;
            a2 += blo(v[j].y) * wj; a3 += bhi(v[j].y) * wj;
            a4 += blo(v[j].z) * wj; a5 += bhi(v[j].z) * wj;
            a6 += blo(v[j].w) * wj; a7 += bhi(v[j].w) * wj;
        }
    }

    if (!active) return;
    uint4 o;
    o.x = packb(a0, a1); o.y = packb(a2, a3);
    o.z = packb(a4, a5); o.w = packb(a6, a7);
    *(uint4*)((unsigned int*)outb + (long)i * 32 + q * 4) = o;
}

// projection: lane l holds W[:,l] as 32 bf16-pair registers. TWO rows per
// iteration (r, r+nW): 32 independent uniform loads in flight, then 128 FMAs
// -- hides the L2 round-trip that serialized the 1-row version (46us, 18% occ).
__global__ void __launch_bounds__(256)
__attribute__((amdgpu_waves_per_eu(2, 4)))
proj_regb(const unsigned short* __restrict__ h2b,
          const float* __restrict__ W, const float* __restrict__ bias,
          float* __restrict__ out, int n) {
    int lane = threadIdx.x & 63;
    int wave = (blockIdx.x * blockDim.x + threadIdx.x) >> 6;
    int nW = (gridDim.x * blockDim.x) >> 6;

    unsigned int wb[32];
    #pragma unroll
    for (int p = 0; p < 32; ++p) {
        wb[p] = packb(W[(2 * p) * D + lane], W[(2 * p + 1) * D + lane]);
    }
    float bl = bias[lane];

    const uint2* h2 = (const uint2*)h2b;
    for (int r = wave; r < n; r += 2 * nW) {
        int r2 = r + nW;
        bool has2 = r2 < n;
        const uint2* hr = h2 + (long)r * 16;
        const uint2* hs = h2 + (long)(has2 ? r2 : r) * 16;
        uint2 ha[16], hc[16];
        #pragma unroll
        for (int c = 0; c < 16; ++c) { ha[c] = hr[c]; hc[c] = hs[c]; }
        float y0 = bl, y1 = 0.f, y2 = 0.f, y3 = 0.f;
        float z0 = bl, z1 = 0.f, z2 = 0.f, z3 = 0.f;
        #pragma unroll
        for (int c = 0; c < 16; ++c) {
            unsigned int wp0 = wb[2 * c];
            unsigned int wp1 = wb[2 * c + 1];
            y0 += blo(ha[c].x) * blo(wp0);
            y1 += bhi(ha[c].x) * bhi(wp0);
            y2 += blo(ha[c].y) * blo(wp1);
            y3 += bhi(ha[c].y) * bhi(wp1);
            z0 += blo(hc[c].x) * blo(wp0);
            z1 += bhi(hc[c].x) * bhi(wp0);
            z2 += blo(hc[c].y) * blo(wp1);
            z3 += bhi(hc[c].y) * bhi(wp1);
        }
        out[(long)r * D + lane] = (y0 + y1) + (y2 + y3);
        if (has2) out[(long)r2 * D + lane] = (z0 + z1) + (z2 + z3);
    }
}

extern "C" void kernel_launch(void* const* d_in, const int* in_sizes, int n_in,
                              void* d_out, int out_size, void* d_ws, size_t ws_size,
                              hipStream_t stream) {
    const float* x    = (const float*)d_in[0];
    const int*   ei   = (const int*)d_in[1];
    const float* ew   = (const float*)d_in[2];
    const float* W    = (const float*)d_in[3];
    const float* bias = (const float*)d_in[4];

    int n = in_sizes[0] / D;   // 100000
    int E = in_sizes[2];       // 1600000
    const int* row = ei;
    const int* col = ei + E;

    float* out = (float*)d_out;

    const int NB = (n + 255) >> 8;        // 391 buckets (<=512 for n<=131072)
    const int BA = 256;                    // blocks in bucket passes
    int chunk = (E + BA - 1) / BA;

    // workspace layout (4-byte units)
    float* dinv  = (float*)d_ws;                  // n
    int*   cnt   = (int*)(dinv + alignup(n));     // n
    int*   bsums = cnt + alignup(n);              // 1024
    int*   off   = bsums + 1024;                  // n
    int*   endp  = off + alignup(n);              // n
    int*   bcnt  = endp + alignup(n);             // 512
    int*   boff  = bcnt + 512;                    // 512
    int*   bhist = boff + 512;                    // NB*256 (<=512*256)
    uint2* csr   = (uint2*)(bhist + alignup(NB * 256)); // E x 8B
    unsigned short* xb  = (unsigned short*)(csr + alignup(E)); // n*D bf16
    unsigned short* h1b = xb + (long)alignup(n) * D;           // n*D bf16
    unsigned short* h2b = h1b + (long)alignup(n) * D;          // n*D bf16
    uint2* ebuf = (uint2*)h2b;  // aliases h2b: consumed before hop2 writes it

    const float fill = 1.0f;  // IMPROVED = False
    const int blk = 256;
    int nbN = (n + blk - 1) / blk;

    long nElem = (long)n * D;
    int nbC = (int)((nElem / 4 + blk - 1) / blk);
    convert_bf16<<<nbC, blk, 0, stream>>>(x, xb, nElem);

    // bucket-sort CSR build (LDS atomics only)
    countA<<<BA, 256, 0, stream>>>(row, bhist, E, chunk, NB);
    scanA<<<NB, 256, 0, stream>>>(bhist, bcnt, NB);
    scan_boff<<<1, 512, 0, stream>>>(bcnt, boff, NB);
    scatterB<<<BA, 256, 0, stream>>>(row, col, ew, bhist, boff, ebuf, E, chunk, NB);
    fineC1<<<NB, 256, 0, stream>>>(ebuf, boff, bcnt, cnt, n);
    scan_block_sums<<<nbN, blk, 0, stream>>>(cnt, bsums, n);
    scan_bsums<<<1, 1024, 0, stream>>>(bsums, nbN);
    scan_final<<<nbN, blk, 0, stream>>>(cnt, bsums, off, endp, n);
    placeC2<<<NB, 256, 0, stream>>>(ebuf, boff, bcnt, off, csr, n);

    seg_dinv<<<nbN, blk, 0, stream>>>(csr, off, endp, dinv, n, fill);
    norm_w<<<nbN, blk, 0, stream>>>(csr, off, endp, dinv, n);

    int nWaves = (n + 7) / 8;
    int nbHop = (nWaves * 64 + blk - 1) / blk;
    hop_g8<<<nbHop, blk, 0, stream>>>(xb, dinv, off, endp, csr, h1b, n);
    hop_g8<<<nbHop, blk, 0, stream>>>(h1b, dinv, off, endp, csr, h2b, n);

    proj_regb<<<1024, blk, 0, stream>>>(h2b, W, bias, out, n);
}

// Round 14
// 188.203 us; speedup vs baseline: 2.1626x; 1.0935x over previous
//
#include <hip/hip_runtime.h>

#define D 64

static __host__ __device__ inline int alignup(int x) { return (x + 63) & ~63; }

__device__ inline float blo(unsigned int u) { return __uint_as_float(u << 16); }
__device__ inline float bhi(unsigned int u) { return __uint_as_float(u & 0xffff0000u); }
__device__ inline unsigned short f2b(float f) {
    unsigned int u = __float_as_uint(f);
    return (unsigned short)((u + 0x7FFFu + ((u >> 16) & 1u)) >> 16);
}
__device__ inline unsigned int packb(float lo, float hi) {
    return (unsigned int)f2b(lo) | ((unsigned int)f2b(hi) << 16);
}

typedef short bf16x8 __attribute__((ext_vector_type(8)));
typedef float f32x4 __attribute__((ext_vector_type(4)));

__global__ void convert_bf16(const float* __restrict__ x, unsigned short* __restrict__ xb, long nElem) {
    long t = (long)blockIdx.x * blockDim.x + threadIdx.x;
    long i = t * 4;
    if (i + 3 < nElem) {
        float4 v = *(const float4*)(x + i);
        ushort4 o;
        o.x = f2b(v.x); o.y = f2b(v.y); o.z = f2b(v.z); o.w = f2b(v.w);
        *(ushort4*)(xb + i) = o;
    } else {
        for (long k = i; k < nElem; ++k) xb[k] = f2b(x[k]);
    }
}

// W [64][64] f32 -> WbT [c][k] bf16 (transposed) for contiguous B-fragments
__global__ void convert_wbt(const float* __restrict__ W, unsigned short* __restrict__ wbt) {
    int idx = blockIdx.x * blockDim.x + threadIdx.x;  // 4096
    int c = idx >> 6, k = idx & 63;
    wbt[c * 64 + k] = f2b(W[k * 64 + c]);
}

// ---------- bucket-sort CSR build: LDS atomics only, ZERO global atomics ----
__global__ void countA(const int* __restrict__ row, int* __restrict__ bhist,
                       int E, int chunk, int NB) {
    __shared__ int h[512];
    int b = blockIdx.x;
    for (int k = threadIdx.x; k < NB; k += blockDim.x) h[k] = 0;
    __syncthreads();
    int s = b * chunk, e = min(s + chunk, E);
    for (int p = s + (int)threadIdx.x; p < e; p += blockDim.x)
        atomicAdd(&h[row[p] >> 8], 1);
    __syncthreads();
    for (int k = threadIdx.x; k < NB; k += blockDim.x)
        bhist[k * 256 + b] = h[k];
}

__global__ void scanA(int* __restrict__ bhist, int* __restrict__ bcnt, int NB) {
    __shared__ int s[256];
    int k = blockIdx.x;
    int t = threadIdx.x;
    int v = bhist[k * 256 + t];
    s[t] = v;
    __syncthreads();
    for (int o = 1; o < 256; o <<= 1) {
        int u = (t >= o) ? s[t - o] : 0;
        __syncthreads();
        if (t >= o) s[t] += u;
        __syncthreads();
    }
    bhist[k * 256 + t] = s[t] - v;
    if (t == 255) bcnt[k] = s[t];
}

__global__ void scan_boff(const int* __restrict__ bcnt, int* __restrict__ boff, int nb) {
    __shared__ int s[512];
    int t = threadIdx.x;
    s[t] = (t < nb) ? bcnt[t] : 0;
    __syncthreads();
    for (int o = 1; o < 512; o <<= 1) {
        int v = (t >= o) ? s[t - o] : 0;
        __syncthreads();
        if (t >= o) s[t] += v;
        __syncthreads();
    }
    if (t < nb) boff[t] = (t == 0) ? 0 : s[t - 1];
}

__global__ void scatterB(const int* __restrict__ row, const int* __restrict__ col,
                         const float* __restrict__ w, const int* __restrict__ bhist,
                         const int* __restrict__ boff, uint2* __restrict__ ebuf,
                         int E, int chunk, int NB) {
    __shared__ int cur[512];
    int b = blockIdx.x;
    for (int k = threadIdx.x; k < NB; k += blockDim.x)
        cur[k] = boff[k] + bhist[k * 256 + b];
    __syncthreads();
    int s = b * chunk, e = min(s + chunk, E);
    for (int p = s + (int)threadIdx.x; p < e; p += blockDim.x) {
        int r = row[p];
        int bkt = r >> 8;
        int pos = atomicAdd(&cur[bkt], 1);
        ebuf[pos] = make_uint2(((unsigned)(r & 255) << 24) | (unsigned)col[p],
                               __float_as_uint(w[p]));
    }
}

__global__ void fineC1(const uint2* __restrict__ ebuf, const int* __restrict__ boff,
                       const int* __restrict__ bcnt, int* __restrict__ cnt, int n) {
    __shared__ int c2[256];
    int k = blockIdx.x;
    c2[threadIdx.x] = 0;
    __syncthreads();
    int s = boff[k], e = s + bcnt[k];
    for (int p = s + (int)threadIdx.x; p < e; p += blockDim.x)
        atomicAdd(&c2[ebuf[p].x >> 24], 1);
    __syncthreads();
    int r = k * 256 + threadIdx.x;
    if (r < n) cnt[r] = c2[threadIdx.x];
}

__global__ void placeC2(const uint2* __restrict__ ebuf, const int* __restrict__ boff,
                        const int* __restrict__ bcnt, const int* __restrict__ off,
                        uint2* __restrict__ csr, int n) {
    __shared__ int c2[256];
    int k = blockIdx.x;
    c2[threadIdx.x] = 0;
    __syncthreads();
    int s = boff[k], e = s + bcnt[k];
    for (int p = s + (int)threadIdx.x; p < e; p += blockDim.x) {
        uint2 ent = ebuf[p];
        int rl = (int)(ent.x >> 24);
        int pos = atomicAdd(&c2[rl], 1);
        int r = k * 256 + rl;
        csr[off[r] + pos] = make_uint2(ent.x & 0xFFFFFFu, ent.y);
    }
}

// ---------- scans over n --------------------------------------------------
__global__ void scan_block_sums(const int* __restrict__ cnt, int* __restrict__ bsums, int n) {
    __shared__ int s[256];
    int t = threadIdx.x;
    int i = blockIdx.x * 256 + t;
    s[t] = (i < n) ? cnt[i] : 0;
    __syncthreads();
    for (int st = 128; st > 0; st >>= 1) {
        if (t < st) s[t] += s[t + st];
        __syncthreads();
    }
    if (t == 0) bsums[blockIdx.x] = s[0];
}

__global__ void scan_bsums(int* __restrict__ bsums, int nb) {
    __shared__ int s[1024];
    int t = threadIdx.x;
    s[t] = (t < nb) ? bsums[t] : 0;
    __syncthreads();
    for (int off = 1; off < 1024; off <<= 1) {
        int v = 0;
        if (t >= off) v = s[t - off];
        __syncthreads();
        if (t >= off) s[t] += v;
        __syncthreads();
    }
    if (t < nb) bsums[t] = (t == 0) ? 0 : s[t - 1];
}

__global__ void scan_final(const int* __restrict__ cnt, const int* __restrict__ bsums,
                           int* __restrict__ off, int* __restrict__ end, int n) {
    __shared__ int s[256];
    int t = threadIdx.x;
    int i = blockIdx.x * 256 + t;
    int v = (i < n) ? cnt[i] : 0;
    s[t] = v;
    __syncthreads();
    for (int o = 1; o < 256; o <<= 1) {
        int u = 0;
        if (t >= o) u = s[t - o];
        __syncthreads();
        if (t >= o) s[t] += u;
        __syncthreads();
    }
    if (i < n) {
        int o0 = bsums[blockIdx.x] + s[t] - v;
        off[i] = o0;
        end[i] = o0 + v;
    }
}

__global__ void seg_dinv(const uint2* __restrict__ csr, const int* __restrict__ off,
                         const int* __restrict__ end, float* __restrict__ dinv,
                         int n, float fill) {
    int i = blockIdx.x * blockDim.x + threadIdx.x;
    if (i >= n) return;
    float d = fill;
    int s = off[i], e = end[i];
    for (int p = s; p < e; ++p) d += __uint_as_float(csr[p].y);
    dinv[i] = d > 0.0f ? rsqrtf(d) : 0.0f;
}

__global__ void norm_w(uint2* __restrict__ csr, const int* __restrict__ off,
                       const int* __restrict__ end, const float* __restrict__ dinv, int n) {
    int i = blockIdx.x * blockDim.x + threadIdx.x;
    if (i >= n) return;
    float di = dinv[i];
    int s = off[i], e = end[i];
    for (int p = s; p < e; ++p) {
        uint2 ent = csr[p];
        float wn = __uint_as_float(ent.y) * di * dinv[(int)ent.x];
        ((float*)csr)[2 * p + 1] = wn;
    }
}

// 8 nodes per wave; 16 CSR entries per iteration, gathers batched into v[16].
__global__ void __launch_bounds__(256)
__attribute__((amdgpu_waves_per_eu(2, 4)))
hop_g8(const unsigned short* __restrict__ xb, const float* __restrict__ dinv,
       const int* __restrict__ off, const int* __restrict__ end,
       const uint2* __restrict__ csr,
       unsigned short* __restrict__ outb, int n) {
    int t = blockIdx.x * blockDim.x + threadIdx.x;
    int wave = t >> 6;
    int lane = t & 63;
    int g = lane >> 3, q = lane & 7;
    int i = wave * 8 + g;
    bool active = i < n;
    int ii = active ? i : n - 1;

    const unsigned int* xw = (const unsigned int*)xb;
    float di = dinv[ii];
    float di2 = di * di;
    uint4 sv = *(const uint4*)(xw + (long)ii * 32 + q * 4);
    float a0 = blo(sv.x) * di2, a1 = bhi(sv.x) * di2;
    float a2 = blo(sv.y) * di2, a3 = bhi(sv.y) * di2;
    float a4 = blo(sv.z) * di2, a5 = bhi(sv.z) * di2;
    float a6 = blo(sv.w) * di2, a7 = bhi(sv.w) * di2;

    int s = active ? off[ii] : 0;
    int e = active ? end[ii] : 0;

    for (int b = s; b < e; b += 16) {
        int i0 = b + q;     if (i0 >= e) i0 = e - 1;
        int i1 = b + 8 + q; if (i1 >= e) i1 = e - 1;
        uint2 e0 = csr[i0];
        uint2 e1 = csr[i1];
        uint4 v[16];
        float wv[16];
        #pragma unroll
        for (int j = 0; j < 16; ++j) {
            int srcl = g * 8 + (j & 7);
            int cb = __shfl((int)(j < 8 ? e0.x : e1.x), srcl, 64);
            float wj = __uint_as_float(__shfl((int)(j < 8 ? e0.y : e1.y), srcl, 64));
            if (b + j >= e) wj = 0.0f;
            wv[j] = wj;
            v[j] = make_uint4(0u, 0u, 0u, 0u);
            if (wj != 0.0f) v[j] = *(const uint4*)(xw + (long)cb * 32 + q * 4);
        }
        #pragma unroll
        for (int j = 0; j < 16; ++j) {
            float wj = wv[j];
            a0 += blo(v[j].x) * wj; a1 += bhi(v[j].x) * wj;
            a2 += blo(v[j].y) * wj; a3 += bhi(v[j].y) * wj;
            a4 += blo(v[j].z) * wj; a5 += bhi(v[j].z) * wj;
            a6 += blo(v[j].w) * wj; a7 += bhi(v[j].w) * wj;
        }
    }

    if (!active) return;
    uint4 o;
    o.x = packb(a0, a1); o.y = packb(a2, a3);
    o.z = packb(a4, a5); o.w = packb(a6, a7);
    *(uint4*)((unsigned int*)outb + (long)i * 32 + q * 4) = o;
}

// MFMA projection: one wave per 16-row tile. A = h2 (bf16, row lane&15,
// k-block (lane>>4)*8, one uint4 per K-step), B = WbT (contiguous frags),
// C/D: col=lane&15, row=(lane>>4)*4+reg (verified layout). Bias in acc init.
__global__ void __launch_bounds__(256)
proj_mfma(const unsigned short* __restrict__ h2b, const unsigned short* __restrict__ wbt,
          const float* __restrict__ bias, float* __restrict__ out, int n) {
    int lane = threadIdx.x & 63;
    int w = (blockIdx.x * blockDim.x + threadIdx.x) >> 6;
    int nTiles = (n + 15) >> 4;
    if (w >= nTiles) return;
    int r0 = w * 16;
    int rl = lane & 15;
    int half = lane >> 4;  // 0..3

    int ar = r0 + rl; if (ar >= n) ar = n - 1;  // clamp for tail tile
    const unsigned short* arow = h2b + (long)ar * 64 + half * 8;
    bf16x8 A0 = __builtin_bit_cast(bf16x8, *(const uint4*)(arow));
    bf16x8 A1 = __builtin_bit_cast(bf16x8, *(const uint4*)(arow + 32));

    #pragma unroll
    for (int t = 0; t < 4; ++t) {
        const unsigned short* bcol = wbt + (long)(t * 16 + rl) * 64 + half * 8;
        bf16x8 B0 = __builtin_bit_cast(bf16x8, *(const uint4*)(bcol));
        bf16x8 B1 = __builtin_bit_cast(bf16x8, *(const uint4*)(bcol + 32));
        float bl = bias[t * 16 + rl];
        f32x4 acc = {bl, bl, bl, bl};
        acc = __builtin_amdgcn_mfma_f32_16x16x32_bf16(A0, B0, acc, 0, 0, 0);
        acc = __builtin_amdgcn_mfma_f32_16x16x32_bf16(A1, B1, acc, 0, 0, 0);
        #pragma unroll
        for (int j = 0; j < 4; ++j) {
            int r = r0 + half * 4 + j;
            if (r < n) out[(long)r * 64 + t * 16 + rl] = acc[j];
        }
    }
}

extern "C" void kernel_launch(void* const* d_in, const int* in_sizes, int n_in,
                              void* d_out, int out_size, void* d_ws, size_t ws_size,
                              hipStream_t stream) {
    const float* x    = (const float*)d_in[0];
    const int*   ei   = (const int*)d_in[1];
    const float* ew   = (const float*)d_in[2];
    const float* W    = (const float*)d_in[3];
    const float* bias = (const float*)d_in[4];

    int n = in_sizes[0] / D;   // 100000
    int E = in_sizes[2];       // 1600000
    const int* row = ei;
    const int* col = ei + E;

    float* out = (float*)d_out;

    const int NB = (n + 255) >> 8;
    const int BA = 256;
    int chunk = (E + BA - 1) / BA;

    // workspace layout (4-byte units)
    float* dinv  = (float*)d_ws;                  // n
    int*   cnt   = (int*)(dinv + alignup(n));     // n
    int*   bsums = cnt + alignup(n);              // 1024
    int*   off   = bsums + 1024;                  // n
    int*   endp  = off + alignup(n);              // n
    int*   bcnt  = endp + alignup(n);             // 512
    int*   boff  = bcnt + 512;                    // 512
    int*   bhist = boff + 512;                    // NB*256
    uint2* csr   = (uint2*)(bhist + alignup(NB * 256)); // E x 8B
    unsigned short* xb  = (unsigned short*)(csr + alignup(E)); // n*D bf16
    unsigned short* h1b = xb + (long)alignup(n) * D;           // n*D bf16
    unsigned short* h2b = h1b + (long)alignup(n) * D;          // n*D bf16
    unsigned short* wbt = h2b + (long)alignup(n) * D;          // 64*64 bf16
    uint2* ebuf = (uint2*)h2b;  // aliases h2b: consumed before hop2 writes it

    const float fill = 1.0f;  // IMPROVED = False
    const int blk = 256;
    int nbN = (n + blk - 1) / blk;

    long nElem = (long)n * D;
    int nbC = (int)((nElem / 4 + blk - 1) / blk);
    convert_bf16<<<nbC, blk, 0, stream>>>(x, xb, nElem);
    convert_wbt<<<16, 256, 0, stream>>>(W, wbt);

    // bucket-sort CSR build (LDS atomics only)
    countA<<<BA, 256, 0, stream>>>(row, bhist, E, chunk, NB);
    scanA<<<NB, 256, 0, stream>>>(bhist, bcnt, NB);
    scan_boff<<<1, 512, 0, stream>>>(bcnt, boff, NB);
    scatterB<<<BA, 256, 0, stream>>>(row, col, ew, bhist, boff, ebuf, E, chunk, NB);
    fineC1<<<NB, 256, 0, stream>>>(ebuf, boff, bcnt, cnt, n);
    scan_block_sums<<<nbN, blk, 0, stream>>>(cnt, bsums, n);
    scan_bsums<<<1, 1024, 0, stream>>>(bsums, nbN);
    scan_final<<<nbN, blk, 0, stream>>>(cnt, bsums, off, endp, n);
    placeC2<<<NB, 256, 0, stream>>>(ebuf, boff, bcnt, off, csr, n);

    seg_dinv<<<nbN, blk, 0, stream>>>(csr, off, endp, dinv, n, fill);
    norm_w<<<nbN, blk, 0, stream>>>(csr, off, endp, dinv, n);

    int nWaves = (n + 7) / 8;
    int nbHop = (nWaves * 64 + blk - 1) / blk;
    hop_g8<<<nbHop, blk, 0, stream>>>(xb, dinv, off, endp, csr, h1b, n);
    hop_g8<<<nbHop, blk, 0, stream>>>(h1b, dinv, off, endp, csr, h2b, n);

    int nTiles = (n + 15) / 16;
    int nbProj = (nTiles * 64 + blk - 1) / blk;
    proj_mfma<<<nbProj, blk, 0, stream>>>(h2b, wbt, bias, out, n);
}

// Round 15
// 159.727 us; speedup vs baseline: 2.5481x; 1.1783x over previous
//
#include <hip/hip_runtime.h>

#define D 64

static __host__ __device__ inline int alignup(int x) { return (x + 63) & ~63; }

__device__ inline float blo(unsigned int u) { return __uint_as_float(u << 16); }
__device__ inline float bhi(unsigned int u) { return __uint_as_float(u & 0xffff0000u); }
__device__ inline unsigned short f2b(float f) {
    unsigned int u = __float_as_uint(f);
    return (unsigned short)((u + 0x7FFFu + ((u >> 16) & 1u)) >> 16);
}
__device__ inline unsigned int packb(float lo, float hi) {
    return (unsigned int)f2b(lo) | ((unsigned int)f2b(hi) << 16);
}

typedef short bf16x8 __attribute__((ext_vector_type(8)));
typedef float f32x4 __attribute__((ext_vector_type(4)));

// merged: blocks < nbC convert x -> bf16; the 16 extra blocks build WbT
__global__ void convert_all(const float* __restrict__ x, unsigned short* __restrict__ xb,
                            const float* __restrict__ W, unsigned short* __restrict__ wbt,
                            long nElem, int nbC) {
    if ((int)blockIdx.x >= nbC) {
        int idx = ((int)blockIdx.x - nbC) * 256 + threadIdx.x;  // 0..4095
        int c = idx >> 6, k = idx & 63;
        wbt[c * 64 + k] = f2b(W[k * 64 + c]);
        return;
    }
    long t = (long)blockIdx.x * blockDim.x + threadIdx.x;
    long i = t * 4;
    if (i + 3 < nElem) {
        float4 v = *(const float4*)(x + i);
        ushort4 o;
        o.x = f2b(v.x); o.y = f2b(v.y); o.z = f2b(v.z); o.w = f2b(v.w);
        *(ushort4*)(xb + i) = o;
    } else {
        for (long k = i; k < nElem; ++k) xb[k] = f2b(x[k]);
    }
}

// ---------- bucket-sort CSR build: LDS atomics only, ZERO global atomics ----
// bucket = row >> 8 (256 rows/bucket). NB <= 512.

__global__ void countA(const int* __restrict__ row, int* __restrict__ bhist,
                       int E, int chunk, int NB) {
    __shared__ int h[512];
    int b = blockIdx.x;
    for (int k = threadIdx.x; k < NB; k += blockDim.x) h[k] = 0;
    __syncthreads();
    int s = b * chunk, e = min(s + chunk, E);
    for (int p = s + (int)threadIdx.x; p < e; p += blockDim.x)
        atomicAdd(&h[row[p] >> 8], 1);
    __syncthreads();
    for (int k = threadIdx.x; k < NB; k += blockDim.x)
        bhist[k * 256 + b] = h[k];
}

__global__ void scanA(int* __restrict__ bhist, int* __restrict__ bcnt, int NB) {
    __shared__ int s[256];
    int k = blockIdx.x;
    int t = threadIdx.x;
    int v = bhist[k * 256 + t];
    s[t] = v;
    __syncthreads();
    for (int o = 1; o < 256; o <<= 1) {
        int u = (t >= o) ? s[t - o] : 0;
        __syncthreads();
        if (t >= o) s[t] += u;
        __syncthreads();
    }
    bhist[k * 256 + t] = s[t] - v;
    if (t == 255) bcnt[k] = s[t];
}

__global__ void scan_boff(const int* __restrict__ bcnt, int* __restrict__ boff, int nb) {
    __shared__ int s[512];
    int t = threadIdx.x;
    s[t] = (t < nb) ? bcnt[t] : 0;
    __syncthreads();
    for (int o = 1; o < 512; o <<= 1) {
        int v = (t >= o) ? s[t - o] : 0;
        __syncthreads();
        if (t >= o) s[t] += v;
        __syncthreads();
    }
    if (t < nb) boff[t] = (t == 0) ? 0 : s[t - 1];
}

// ebuf entry: .x = (rowloc<<24) | col  (col < 2^24), .y = raw weight bits
__global__ void scatterB(const int* __restrict__ row, const int* __restrict__ col,
                         const float* __restrict__ w, const int* __restrict__ bhist,
                         const int* __restrict__ boff, uint2* __restrict__ ebuf,
                         int E, int chunk, int NB) {
    __shared__ int cur[512];
    int b = blockIdx.x;
    for (int k = threadIdx.x; k < NB; k += blockDim.x)
        cur[k] = boff[k] + bhist[k * 256 + b];
    __syncthreads();
    int s = b * chunk, e = min(s + chunk, E);
    for (int p = s + (int)threadIdx.x; p < e; p += blockDim.x) {
        int r = row[p];
        int bkt = r >> 8;
        int pos = atomicAdd(&cur[bkt], 1);
        ebuf[pos] = make_uint2(((unsigned)(r & 255) << 24) | (unsigned)col[p],
                               __float_as_uint(w[p]));
    }
}

// ONE kernel per bucket: count + weight-sum (LDS) -> dinv -> LDS scan ->
// off/end -> place into csr (row-tag kept in csr.x for normB).
// Replaces fineC1 + 3 scan kernels + placeC2 + seg_dinv.
__global__ void bucketC(const uint2* __restrict__ ebuf, const int* __restrict__ boff,
                        const int* __restrict__ bcnt, float* __restrict__ dinv,
                        int* __restrict__ off, int* __restrict__ endp,
                        uint2* __restrict__ csr, int n, float fill) {
    __shared__ int cntS[256];
    __shared__ float wsum[256];
    __shared__ int scanS[256];
    __shared__ int cur[256];
    int k = blockIdx.x;
    int t = threadIdx.x;
    cntS[t] = 0;
    wsum[t] = 0.f;
    __syncthreads();
    int s = boff[k], e = s + bcnt[k];
    for (int p = s + t; p < e; p += 256) {
        uint2 ent = ebuf[p];
        int rl = (int)(ent.x >> 24);
        atomicAdd(&cntS[rl], 1);
        atomicAdd(&wsum[rl], __uint_as_float(ent.y));
    }
    __syncthreads();
    int r = k * 256 + t;
    int v = cntS[t];
    if (r < n) {
        float d = fill + wsum[t];
        dinv[r] = d > 0.0f ? rsqrtf(d) : 0.0f;
    }
    scanS[t] = v;
    __syncthreads();
    for (int o = 1; o < 256; o <<= 1) {
        int u = (t >= o) ? scanS[t - o] : 0;
        __syncthreads();
        if (t >= o) scanS[t] += u;
        __syncthreads();
    }
    int base = boff[k] + scanS[t] - v;  // exclusive prefix within bucket
    cur[t] = base;
    if (r < n) { off[r] = base; endp[r] = base + v; }
    __syncthreads();
    for (int p = s + t; p < e; p += 256) {
        uint2 ent = ebuf[p];
        int rl = (int)(ent.x >> 24);
        int pos = atomicAdd(&cur[rl], 1);
        csr[pos] = ent;  // keep rl tag; normB strips it
    }
}

// per-bucket streaming normalize: wn = w * dinv[r] (LDS) * dinv[c]; strip tag.
__global__ void normB(uint2* __restrict__ csr, const int* __restrict__ boff,
                      const int* __restrict__ bcnt, const float* __restrict__ dinv, int n) {
    __shared__ float dl[256];
    int k = blockIdx.x;
    int t = threadIdx.x;
    int r = k * 256 + t;
    dl[t] = (r < n) ? dinv[r] : 0.f;
    __syncthreads();
    int s = boff[k], e = s + bcnt[k];
    for (int p = s + t; p < e; p += 256) {
        uint2 ent = csr[p];
        int rl = (int)(ent.x >> 24);
        unsigned c = ent.x & 0xFFFFFFu;
        float wn = __uint_as_float(ent.y) * dl[rl] * dinv[c];
        csr[p] = make_uint2(c, __float_as_uint(wn));
    }
}

// 8 nodes per wave; 16 CSR entries per iteration, gathers batched into v[16].
__global__ void __launch_bounds__(256)
__attribute__((amdgpu_waves_per_eu(2, 4)))
hop_g8(const unsigned short* __restrict__ xb, const float* __restrict__ dinv,
       const int* __restrict__ off, const int* __restrict__ end,
       const uint2* __restrict__ csr,
       unsigned short* __restrict__ outb, int n) {
    int t = blockIdx.x * blockDim.x + threadIdx.x;
    int wave = t >> 6;
    int lane = t & 63;
    int g = lane >> 3, q = lane & 7;
    int i = wave * 8 + g;
    bool active = i < n;
    int ii = active ? i : n - 1;

    const unsigned int* xw = (const unsigned int*)xb;
    float di = dinv[ii];
    float di2 = di * di;  // self-loop weight (fill=1): dinv^2
    uint4 sv = *(const uint4*)(xw + (long)ii * 32 + q * 4);
    float a0 = blo(sv.x) * di2, a1 = bhi(sv.x) * di2;
    float a2 = blo(sv.y) * di2, a3 = bhi(sv.y) * di2;
    float a4 = blo(sv.z) * di2, a5 = bhi(sv.z) * di2;
    float a6 = blo(sv.w) * di2, a7 = bhi(sv.w) * di2;

    int s = active ? off[ii] : 0;
    int e = active ? end[ii] : 0;

    for (int b = s; b < e; b += 16) {
        int i0 = b + q;     if (i0 >= e) i0 = e - 1;
        int i1 = b + 8 + q; if (i1 >= e) i1 = e - 1;
        uint2 e0 = csr[i0];
        uint2 e1 = csr[i1];
        uint4 v[16];
        float wv[16];
        #pragma unroll
        for (int j = 0; j < 16; ++j) {
            int srcl = g * 8 + (j & 7);
            int cb = __shfl((int)(j < 8 ? e0.x : e1.x), srcl, 64);
            float wj = __uint_as_float(__shfl((int)(j < 8 ? e0.y : e1.y), srcl, 64));
            if (b + j >= e) wj = 0.0f;
            wv[j] = wj;
            v[j] = make_uint4(0u, 0u, 0u, 0u);
            if (wj != 0.0f) v[j] = *(const uint4*)(xw + (long)cb * 32 + q * 4);
        }
        #pragma unroll
        for (int j = 0; j < 16; ++j) {
            float wj = wv[j];
            a0 += blo(v[j].x) * wj; a1 += bhi(v[j].x) * wj;
            a2 += blo(v[j].y) * wj; a3 += bhi(v[j].y) * wj;
            a4 += blo(v[j].z) * wj; a5 += bhi(v[j].z) * wj;
            a6 += blo(v[j].w) * wj; a7 += bhi(v[j].w) * wj;
        }
    }

    if (!active) return;
    uint4 o;
    o.x = packb(a0, a1); o.y = packb(a2, a3);
    o.z = packb(a4, a5); o.w = packb(a6, a7);
    *(uint4*)((unsigned int*)outb + (long)i * 32 + q * 4) = o;
}

// MFMA projection: one wave per 16-row tile (verified C/D layout).
__global__ void __launch_bounds__(256)
proj_mfma(const unsigned short* __restrict__ h2b, const unsigned short* __restrict__ wbt,
          const float* __restrict__ bias, float* __restrict__ out, int n) {
    int lane = threadIdx.x & 63;
    int w = (blockIdx.x * blockDim.x + threadIdx.x) >> 6;
    int nTiles = (n + 15) >> 4;
    if (w >= nTiles) return;
    int r0 = w * 16;
    int rl = lane & 15;
    int half = lane >> 4;  // 0..3

    int ar = r0 + rl; if (ar >= n) ar = n - 1;
    const unsigned short* arow = h2b + (long)ar * 64 + half * 8;
    bf16x8 A0 = __builtin_bit_cast(bf16x8, *(const uint4*)(arow));
    bf16x8 A1 = __builtin_bit_cast(bf16x8, *(const uint4*)(arow + 32));

    #pragma unroll
    for (int t = 0; t < 4; ++t) {
        const unsigned short* bcol = wbt + (long)(t * 16 + rl) * 64 + half * 8;
        bf16x8 B0 = __builtin_bit_cast(bf16x8, *(const uint4*)(bcol));
        bf16x8 B1 = __builtin_bit_cast(bf16x8, *(const uint4*)(bcol + 32));
        float bl = bias[t * 16 + rl];
        f32x4 acc = {bl, bl, bl, bl};
        acc = __builtin_amdgcn_mfma_f32_16x16x32_bf16(A0, B0, acc, 0, 0, 0);
        acc = __builtin_amdgcn_mfma_f32_16x16x32_bf16(A1, B1, acc, 0, 0, 0);
        #pragma unroll
        for (int j = 0; j < 4; ++j) {
            int r = r0 + half * 4 + j;
            if (r < n) out[(long)r * 64 + t * 16 + rl] = acc[j];
        }
    }
}

extern "C" void kernel_launch(void* const* d_in, const int* in_sizes, int n_in,
                              void* d_out, int out_size, void* d_ws, size_t ws_size,
                              hipStream_t stream) {
    const float* x    = (const float*)d_in[0];
    const int*   ei   = (const int*)d_in[1];
    const float* ew   = (const float*)d_in[2];
    const float* W    = (const float*)d_in[3];
    const float* bias = (const float*)d_in[4];

    int n = in_sizes[0] / D;   // 100000
    int E = in_sizes[2];       // 1600000
    const int* row = ei;
    const int* col = ei + E;

    float* out = (float*)d_out;

    const int NB = (n + 255) >> 8;   // 391 buckets
    const int BA = 256;
    int chunk = (E + BA - 1) / BA;

    // workspace layout (4-byte units)
    float* dinv  = (float*)d_ws;                  // n
    int*   off   = (int*)(dinv + alignup(n));     // n
    int*   endp  = off + alignup(n);              // n
    int*   bcnt  = endp + alignup(n);             // 512
    int*   boff  = bcnt + 512;                    // 512
    int*   bhist = boff + 512;                    // NB*256
    uint2* csr   = (uint2*)(bhist + alignup(NB * 256)); // E x 8B
    unsigned short* xb  = (unsigned short*)(csr + alignup(E)); // n*D bf16
    unsigned short* h1b = xb + (long)alignup(n) * D;           // n*D bf16
    unsigned short* h2b = h1b + (long)alignup(n) * D;          // n*D bf16
    unsigned short* wbt = h2b + (long)alignup(n) * D;          // 64*64 bf16
    uint2* ebuf = (uint2*)h2b;  // aliases h2b: consumed before hop2 writes it

    const float fill = 1.0f;  // IMPROVED = False
    const int blk = 256;

    long nElem = (long)n * D;
    int nbC = (int)((nElem / 4 + blk - 1) / blk);
    convert_all<<<nbC + 16, blk, 0, stream>>>(x, xb, W, wbt, nElem, nbC);

    // bucket-sort CSR build (LDS atomics only, no global scan over n)
    countA<<<BA, 256, 0, stream>>>(row, bhist, E, chunk, NB);
    scanA<<<NB, 256, 0, stream>>>(bhist, bcnt, NB);
    scan_boff<<<1, 512, 0, stream>>>(bcnt, boff, NB);
    scatterB<<<BA, 256, 0, stream>>>(row, col, ew, bhist, boff, ebuf, E, chunk, NB);
    bucketC<<<NB, 256, 0, stream>>>(ebuf, boff, bcnt, dinv, off, endp, csr, n, fill);
    normB<<<NB, 256, 0, stream>>>(csr, boff, bcnt, dinv, n);

    int nWaves = (n + 7) / 8;
    int nbHop = (nWaves * 64 + blk - 1) / blk;
    hop_g8<<<nbHop, blk, 0, stream>>>(xb, dinv, off, endp, csr, h1b, n);
    hop_g8<<<nbHop, blk, 0, stream>>>(h1b, dinv, off, endp, csr, h2b, n);

    int nTiles = (n + 15) / 16;
    int nbProj = (nTiles * 64 + blk - 1) / blk;
    proj_mfma<<<nbProj, blk, 0, stream>>>(h2b, wbt, bias, out, n);
}